// Round 1
// baseline (183.487 us; speedup 1.0000x reference)
//
#include <hip/hip_runtime.h>
#include <math.h>

#define B_ 4
#define N_ 33600
#define G_ 100
#define NCLS 80
#define STRIDE 85   // 4 box + 80 cls + 1 obj
#define TK 10

__device__ __forceinline__ float sigmoidf_(float x) {
    return 1.0f / (1.0f + expf(-x));
}
__device__ __forceinline__ float softplusf_(float x) {
    return fmaxf(x, 0.0f) + log1pf(expf(-fabsf(x)));
}

// ---------------------------------------------------------------- stage 1
// candidate mask: anchor within CENTER_RADIUS of any GT center
__global__ void k_cand(const float* __restrict__ gtb,
                       const float* __restrict__ anc,
                       unsigned char* __restrict__ mask)
{
    __shared__ float gx[G_], gy[G_];
    const int b = blockIdx.y;
    const int tid = threadIdx.x;
    if (tid < G_) {
        gx[tid] = gtb[(b * G_ + tid) * 4 + 0];
        gy[tid] = gtb[(b * G_ + tid) * 4 + 1];
    }
    __syncthreads();
    const int n = blockIdx.x * blockDim.x + tid;
    if (n >= N_) return;
    const float ax = anc[n * 2 + 0], ay = anc[n * 2 + 1];
    unsigned char c = 0;
    for (int g = 0; g < G_; ++g) {
        const float dx = ax - gx[g], dy = ay - gy[g];
        if (dx * dx + dy * dy < 6.25f) { c = 1; break; }
    }
    mask[b * N_ + n] = c;
}

// ---------------------------------------------------------------- stage 2
// ordered compaction of candidate indices; one block per image
__global__ void k_compact(const unsigned char* __restrict__ mask,
                          int* __restrict__ cidx,
                          int* __restrict__ counts) // [b][0]=n_cand, [b][1]=all_cand
{
    const int b = blockIdx.x;
    const int tid = threadIdx.x;
    const int lane = tid & 63, wid = tid >> 6;
    __shared__ int wsum[4];
    int base = 0;
    const int CH = 1024; // 256 threads * 4 bytes
    for (int chunk = 0; chunk * CH < N_; ++chunk) {
        const int i0 = chunk * CH + tid * 4;
        unsigned m0 = 0, m1 = 0, m2 = 0, m3 = 0;
        if (i0 + 3 < N_) {  // N_ % 4 == 0, so in-range is all-or-nothing
            const uchar4 v = *reinterpret_cast<const uchar4*>(&mask[b * N_ + i0]);
            m0 = v.x; m1 = v.y; m2 = v.z; m3 = v.w;
        }
        int cnt = (int)(m0 + m1 + m2 + m3);
        int incl = cnt;
        #pragma unroll
        for (int off = 1; off < 64; off <<= 1) {
            const int v = __shfl_up(incl, off, 64);
            if (lane >= off) incl += v;
        }
        if (lane == 63) wsum[wid] = incl;
        __syncthreads();
        int wbase = 0;
        for (int w = 0; w < wid; ++w) wbase += wsum[w];
        const int ctot = wsum[0] + wsum[1] + wsum[2] + wsum[3];
        int pos = base + wbase + (incl - cnt);
        if (m0) cidx[b * N_ + pos++] = i0 + 0;
        if (m1) cidx[b * N_ + pos++] = i0 + 1;
        if (m2) cidx[b * N_ + pos++] = i0 + 2;
        if (m3) cidx[b * N_ + pos++] = i0 + 3;
        base += ctot;
        __syncthreads();
    }
    if (tid == 0) {
        counts[b * 2 + 0] = base;
        counts[b * 2 + 1] = (base == 0) ? 1 : 0; // fallback: all anchors candidates
    }
}

// ---------------------------------------------------------------- stage 3
// per candidate: sum_c softplus(sigmoid(cls_logit))
__global__ void k_spsum(const float* __restrict__ pred,
                        const int* __restrict__ cidx,
                        const int* __restrict__ counts,
                        float* __restrict__ spsum)
{
    const int b = blockIdx.y;
    const int cnt = counts[b * 2 + 0];
    const int allc = counts[b * 2 + 1];
    const int count = allc ? N_ : cnt;
    const int i = blockIdx.x * blockDim.x + threadIdx.x;
    if (i >= count) return;
    const int n = allc ? i : cidx[b * N_ + i];
    const float* row = pred + (size_t)(b * N_ + n) * STRIDE + 4;
    float s = 0.0f;
    for (int c = 0; c < NCLS; ++c) {
        s += softplusf_(sigmoidf_(row[c]));
    }
    spsum[b * N_ + i] = s;
}

// ---------------------------------------------------------------- stage 4
// one wave per (b,g): iou col-sum -> dyn_k; stable top-10 smallest cost;
// scatter atomicMin((cost_bits<<32)|g) per kept anchor.
__global__ void __launch_bounds__(64)
k_topk(const float* __restrict__ pred,
       const float* __restrict__ gtb,
       const int* __restrict__ gtc,
       const int* __restrict__ cidx,
       const int* __restrict__ counts,
       const float* __restrict__ spsum,
       unsigned long long* __restrict__ bkey)
{
    const int b = blockIdx.y, g = blockIdx.x;
    const int lane = threadIdx.x;
    const int cnt = counts[b * 2 + 0];
    const int allc = counts[b * 2 + 1];
    const int count = allc ? N_ : cnt;

    const float* gb = gtb + (b * G_ + g) * 4;
    const float gxc = gb[0], gyc = gb[1], gw = gb[2], gh = gb[3];
    const float gx1 = gxc - gw * 0.5f, gy1 = gyc - gh * 0.5f;
    const float gx2 = gxc + gw * 0.5f, gy2 = gyc + gh * 0.5f;
    const float garea = gw * gh;
    const int cls = gtc[b * G_ + g];

    float kcost[TK];
    int   kslot[TK];
    #pragma unroll
    for (int j = 0; j < TK; ++j) { kcost[j] = INFINITY; kslot[j] = 0x7FFFFFFF; }

    float iousum = 0.0f;
    for (int i = lane; i < count; i += 64) {
        const int n = allc ? i : cidx[b * N_ + i];
        const float* pr = pred + (size_t)(b * N_ + n) * STRIDE;
        const float px = pr[0], py = pr[1], pw = pr[2], ph = pr[3];
        const float x1 = px - pw * 0.5f, y1 = py - ph * 0.5f;
        const float x2 = px + pw * 0.5f, y2 = py + ph * 0.5f;
        const float iw = fmaxf(fminf(x2, gx2) - fmaxf(x1, gx1), 0.0f);
        const float ih = fmaxf(fminf(y2, gy2) - fmaxf(y1, gy1), 0.0f);
        const float inter = iw * ih;
        const float uni = pw * ph + garea - inter + 1e-7f;
        const float iou = inter / uni;
        iousum += iou;
        const float sgc = sigmoidf_(pr[4 + cls]);
        float c = -logf(iou + 1e-8f) + 3.0f * (spsum[b * N_ + i] - sgc);
        int   s = i;
        // bubble-insert; slots within a lane strictly increase, so strict <
        // preserves lexicographic (cost, slot) order.
        #pragma unroll
        for (int j = 0; j < TK; ++j) {
            const bool lt = (c < kcost[j]);
            const float tc = kcost[j]; const int ts = kslot[j];
            if (lt) { kcost[j] = c; kslot[j] = s; c = tc; s = ts; }
        }
    }

    // wave-sum of iou column
    #pragma unroll
    for (int off = 32; off; off >>= 1) iousum += __shfl_xor(iousum, off, 64);

    // 10 rounds of wave-wide extract-min on packed (cost_bits, slot) keys.
    // cost > 0 always (cls_cost >= ~54), so float bits are order-preserving.
    unsigned long long win[TK];
    #pragma unroll
    for (int r = 0; r < TK; ++r) {
        const unsigned long long mykey =
            ((unsigned long long)__float_as_uint(kcost[0]) << 32) | (unsigned)kslot[0];
        unsigned long long k2 = mykey;
        #pragma unroll
        for (int off = 32; off; off >>= 1) {
            const unsigned long long o = __shfl_xor(k2, off, 64);
            k2 = (o < k2) ? o : k2;
        }
        win[r] = k2;
        if (mykey == k2) { // unique (slot unique per lane); pop my head
            #pragma unroll
            for (int j = 0; j < TK - 1; ++j) { kcost[j] = kcost[j + 1]; kslot[j] = kslot[j + 1]; }
            kcost[TK - 1] = INFINITY; kslot[TK - 1] = 0x7FFFFFFF;
        }
    }

    const int kmax = (count < TK) ? count : TK;
    int dk = (int)floorf(iousum);
    if (dk < 1) dk = 1;
    if (dk > kmax) dk = kmax;

    if (lane == 0) {
        #pragma unroll
        for (int r = 0; r < TK; ++r) {
            if (r < dk) {
                const unsigned slot = (unsigned)(win[r] & 0xFFFFFFFFull);
                const int n = allc ? (int)slot : cidx[b * N_ + (int)slot];
                const unsigned cbits = (unsigned)(win[r] >> 32);
                const unsigned long long key =
                    ((unsigned long long)cbits << 32) | (unsigned)g;
                atomicMin(&bkey[(size_t)b * N_ + n], key);
            }
        }
    }
}

// ---------------------------------------------------------------- stage 5
// per-anchor losses + fixed-order block reduction
__global__ void k_loss(const float* __restrict__ pred,
                       const float* __restrict__ gtb,
                       const int* __restrict__ gtc,
                       const unsigned long long* __restrict__ bkey,
                       float* __restrict__ partials)
{
    const int b = blockIdx.y;
    const int tid = threadIdx.x;
    const int n = blockIdx.x * blockDim.x + tid;
    float obj = 0.0f, box = 0.0f, cls = 0.0f, npos = 0.0f;
    if (n < N_) {
        const float* pr = pred + (size_t)(b * N_ + n) * STRIDE;
        const float po = pr[STRIDE - 1];
        const unsigned long long key = bkey[(size_t)b * N_ + n];
        const bool fg = (key != 0xFFFFFFFFFFFFFFFFull);
        obj = softplusf_(po) - (fg ? po : 0.0f);
        if (fg) {
            npos = 1.0f;
            const int mg = (int)(unsigned)(key & 0xFFFFFFFFull);
            const float* gb = gtb + (b * G_ + mg) * 4;
            const float px = pr[0], py = pr[1], pw = pr[2], ph = pr[3];
            const float gx = gb[0], gy = gb[1], gw = gb[2], gh = gb[3];
            const float x11 = px - pw * 0.5f, y11 = py - ph * 0.5f;
            const float x12 = px + pw * 0.5f, y12 = py + ph * 0.5f;
            const float x21 = gx - gw * 0.5f, y21 = gy - gh * 0.5f;
            const float x22 = gx + gw * 0.5f, y22 = gy + gh * 0.5f;
            const float iw = fmaxf(fminf(x12, x22) - fmaxf(x11, x21), 0.0f);
            const float ih = fmaxf(fminf(y12, y22) - fmaxf(y11, y21), 0.0f);
            const float inter = iw * ih;
            const float uni = pw * ph + gw * gh - inter + 1e-7f;
            const float iou = inter / uni;
            const float cw = fmaxf(x12, x22) - fminf(x11, x21);
            const float chh = fmaxf(y12, y22) - fminf(y11, y21);
            const float c2 = cw * cw + chh * chh + 1e-7f;
            const float ddx = x11 + x12 - x21 - x22;
            const float ddy = y11 + y12 - y21 - y22;
            const float rho2 = (ddx * ddx + ddy * ddy) * 0.25f;
            const float dv = atanf(gw / (gh + 1e-7f)) - atanf(pw / (ph + 1e-7f));
            const float v = (float)(4.0 / (M_PI * M_PI)) * dv * dv;
            const float alpha = v / (v - iou + 1.0f + 1e-7f);
            const float ciou = iou - (rho2 / c2 + v * alpha);
            box = 1.0f - ciou;
            const int cg = gtc[b * G_ + mg];
            float csum = 0.0f;
            for (int c = 0; c < NCLS; ++c) {
                const float x = pr[4 + c];
                const float t = (c == cg) ? 1.0f : 0.0f;
                const float bce = softplusf_(x) - x * t;
                const float p = sigmoidf_(x);
                const float pt = (c == cg) ? p : (1.0f - p);
                const float om = 1.0f - pt;
                csum += 0.25f * om * om * bce;
            }
            cls = csum;
        }
    }
    __shared__ float red[256];
    float out4[4] = {obj, box, cls, npos};
    float res[4];
    #pragma unroll
    for (int k = 0; k < 4; ++k) {
        red[tid] = out4[k];
        __syncthreads();
        for (int s = 128; s > 0; s >>= 1) {
            if (tid < s) red[tid] += red[tid + s];
            __syncthreads();
        }
        res[k] = red[0];
        __syncthreads();
    }
    if (tid == 0) {
        const int bid = blockIdx.y * gridDim.x + blockIdx.x;
        ((float4*)partials)[bid] = make_float4(res[0], res[1], res[2], res[3]);
    }
}

// ---------------------------------------------------------------- stage 6
__global__ void k_final(const float* __restrict__ partials, int nblocks,
                        float* __restrict__ out)
{
    const int tid = threadIdx.x;
    float so = 0, sb = 0, sc = 0, sn = 0;
    for (int i = tid; i < nblocks; i += 256) {
        const float4 v = ((const float4*)partials)[i];
        so += v.x; sb += v.y; sc += v.z; sn += v.w;
    }
    __shared__ float red[256];
    float in4[4] = {so, sb, sc, sn};
    float res[4];
    #pragma unroll
    for (int k = 0; k < 4; ++k) {
        red[tid] = in4[k];
        __syncthreads();
        for (int s = 128; s > 0; s >>= 1) {
            if (tid < s) red[tid] += red[tid + s];
            __syncthreads();
        }
        res[k] = red[0];
        __syncthreads();
    }
    if (tid == 0) {
        const float n_pos = fmaxf(res[3], 1.0f);
        const float total = 7.5f * res[1] / n_pos
                          + 0.5f * res[2] / n_pos
                          + res[0] / (float)N_;
        out[0] = total;
    }
}

extern "C" void kernel_launch(void* const* d_in, const int* in_sizes, int n_in,
                              void* d_out, int out_size, void* d_ws, size_t ws_size,
                              hipStream_t stream)
{
    const float* pred = (const float*)d_in[0];
    const float* gtb  = (const float*)d_in[1];
    const int*   gtc  = (const int*)d_in[2];
    const float* anc  = (const float*)d_in[3];

    char* ws = (char*)d_ws;
    size_t off = 0;
    auto take = [&](size_t bytes) {
        size_t o = off;
        off += (bytes + 255) & ~(size_t)255;
        return o;
    };
    unsigned char*      mask   = (unsigned char*)(ws + take((size_t)B_ * N_));
    int*                cidx   = (int*)(ws + take((size_t)B_ * N_ * 4));
    float*              spsum  = (float*)(ws + take((size_t)B_ * N_ * 4));
    int*                counts = (int*)(ws + take((size_t)B_ * 2 * 4));
    unsigned long long* bkey   = (unsigned long long*)(ws + take((size_t)B_ * N_ * 8));
    const int nblk = (N_ + 255) / 256; // 132
    float*              partials = (float*)(ws + take((size_t)nblk * B_ * 4 * 4));

    hipMemsetAsync(bkey, 0xFF, (size_t)B_ * N_ * 8, stream);

    dim3 gA(nblk, B_);
    k_cand<<<gA, 256, 0, stream>>>(gtb, anc, mask);
    k_compact<<<B_, 256, 0, stream>>>(mask, cidx, counts);
    k_spsum<<<gA, 256, 0, stream>>>(pred, cidx, counts, spsum);
    dim3 gT(G_, B_);
    k_topk<<<gT, 64, 0, stream>>>(pred, gtb, gtc, cidx, counts, spsum, bkey);
    k_loss<<<gA, 256, 0, stream>>>(pred, gtb, gtc, bkey, partials);
    k_final<<<1, 256, 0, stream>>>(partials, nblk * B_, (float*)d_out);
}